// Round 2
// baseline (2336.464 us; speedup 1.0000x reference)
//
#include <hip/hip_runtime.h>
#include <math.h>

#define DD 256
#define KK 8192
#define NN 16384
#define DECAYF 0.99f
#define EPSF 1e-5f
#define TAU 1e-3f

// output layout (floats)
#define O_Q    0
#define O_LOSS 4194304
#define O_PERP 4194305
#define O_IDX  4194306
#define O_EMB  4210690

// workspace layout (float offsets)
#define WS_COUNTS 0
#define WS_LOSS   8192
#define WS_LISTC  8193
#define WS_LIST   8194
#define WS_ESQ    24832
#define WS_CSN    33024
#define WS_IDX    41216
#define WS_KEY    57600   // byte offset 230400, 8-aligned; 16384 u64 = 32768 floats

// ---------------- column squared norms of embeddings [D,K] (fp64 acc) -------
__global__ void k_colsq(const float* __restrict__ emb, float* __restrict__ esq) {
  int k = blockIdx.x * 256 + threadIdx.x;
  double s = 0.0;
  for (int d = 0; d < DD; ++d) {
    double v = (double)emb[(size_t)d * KK + k];
    s = fma(v, v, s);
  }
  esq[k] = (float)s;
}

// ---------------- init new_embeddings output: 0.99*ema_dw (train) or emb ----
__global__ void k_init_emb(const float* __restrict__ ema_dw, const float* __restrict__ emb,
                           const int* __restrict__ train, float* __restrict__ out4) {
  int i = blockIdx.x * 256 + threadIdx.x; // float2 index, 1048576 total
  int tr = *train;
  const float2* src = tr ? (const float2*)ema_dw : (const float2*)emb;
  float2 v = src[i];
  if (tr) { v.x *= DECAYF; v.y *= DECAYF; }
  ((float2*)out4)[i] = v;
}

// ---------------- main distance + argmin kernel ----------------
// 256 blocks x 256 threads; each block owns 64 rows, scans all K.
// Screening metric: dd = esq[k] - 2*dot (xsq is row-constant -> same argmin,
// and dropping it cuts k-dependent fp32 rounding from ~3e-5 to ~2e-6).
// Rows whose (min2-min1) gap < TAU get fp64-rescored later.
__launch_bounds__(256, 1)
__global__ void k_dist(const float* __restrict__ x, const float* __restrict__ emb,
                       const float* __restrict__ esq, int* __restrict__ idxo,
                       int* __restrict__ listc, int* __restrict__ list) {
  __shared__ __align__(16) float sA[2][32 * 68]; // [d][m] tiles, pad stride 68
  __shared__ __align__(16) float sB[2][32 * 72]; // [d][k] tiles, pad stride 72

  const int tid = threadIdx.x;
  const int tx = tid & 15;       // col group (4 cols each)
  const int ty = tid >> 4;       // row group (4 rows each)
  const int row0 = blockIdx.x * 64;
  const float4* xf4 = (const float4*)x;
  const float4* ef4 = (const float4*)emb;

  float minv[4], min2[4];
  int   mini[4];
  #pragma unroll
  for (int i = 0; i < 4; ++i) { minv[i] = 3.402823466e+38f; min2[i] = 3.402823466e+38f; mini[i] = 0; }

  float4 ra0, ra1, rb0, rb1;

  auto loadTile = [&](int ti) {
    int kt = ti >> 3, dt = ti & 7;
    int d0 = dt * 32, k0 = kt * 64;
    {
      int f = tid;        int m = f >> 3, dq = f & 7;
      ra0 = xf4[(size_t)(row0 + m) * (DD / 4) + (d0 >> 2) + dq];
    }
    {
      int f = tid + 256;  int m = f >> 3, dq = f & 7;
      ra1 = xf4[(size_t)(row0 + m) * (DD / 4) + (d0 >> 2) + dq];
    }
    {
      int f = tid;        int d = f >> 4, kq = f & 15;
      rb0 = ef4[(size_t)(d0 + d) * (KK / 4) + (k0 >> 2) + kq];
    }
    {
      int f = tid + 256;  int d = f >> 4, kq = f & 15;
      rb1 = ef4[(size_t)(d0 + d) * (KK / 4) + (k0 >> 2) + kq];
    }
  };

  auto storeTile = [&](int b) {
    {
      int f = tid;        int m = f >> 3, dq = f & 7;
      sA[b][(dq * 4 + 0) * 68 + m] = ra0.x;
      sA[b][(dq * 4 + 1) * 68 + m] = ra0.y;
      sA[b][(dq * 4 + 2) * 68 + m] = ra0.z;
      sA[b][(dq * 4 + 3) * 68 + m] = ra0.w;
    }
    {
      int f = tid + 256;  int m = f >> 3, dq = f & 7;
      sA[b][(dq * 4 + 0) * 68 + m] = ra1.x;
      sA[b][(dq * 4 + 1) * 68 + m] = ra1.y;
      sA[b][(dq * 4 + 2) * 68 + m] = ra1.z;
      sA[b][(dq * 4 + 3) * 68 + m] = ra1.w;
    }
    {
      int f = tid;        int d = f >> 4, kq = f & 15;
      *(float4*)&sB[b][d * 72 + kq * 4] = rb0;
    }
    {
      int f = tid + 256;  int d = f >> 4, kq = f & 15;
      *(float4*)&sB[b][d * 72 + kq * 4] = rb1;
    }
  };

  loadTile(0);
  storeTile(0);
  loadTile(1);
  int buf = 0;

  for (int kt = 0; kt < 128; ++kt) {
    float accs[4][4];
    #pragma unroll
    for (int i = 0; i < 4; ++i)
      #pragma unroll
      for (int j = 0; j < 4; ++j) accs[i][j] = 0.f;

    for (int dt = 0; dt < 8; ++dt) {
      int ti = kt * 8 + dt;
      __syncthreads();
      if (ti + 1 < 1024) storeTile(buf ^ 1);
      if (ti + 2 < 1024) loadTile(ti + 2);

      const float* As = sA[buf];
      const float* Bs = sB[buf];
      float acc[4][4];
      #pragma unroll
      for (int i = 0; i < 4; ++i)
        #pragma unroll
        for (int j = 0; j < 4; ++j) acc[i][j] = 0.f;

      #pragma unroll
      for (int d = 0; d < 32; ++d) {
        float4 av = *(const float4*)(As + d * 68 + ty * 4);
        float4 bv = *(const float4*)(Bs + d * 72 + tx * 4);
        float a_[4] = {av.x, av.y, av.z, av.w};
        float b_[4] = {bv.x, bv.y, bv.z, bv.w};
        #pragma unroll
        for (int i = 0; i < 4; ++i)
          #pragma unroll
          for (int j = 0; j < 4; ++j)
            acc[i][j] = fmaf(a_[i], b_[j], acc[i][j]);
      }
      #pragma unroll
      for (int i = 0; i < 4; ++i)
        #pragma unroll
        for (int j = 0; j < 4; ++j) accs[i][j] += acc[i][j];

      buf ^= 1;
    }

    // epilogue: dd = esq - 2*dot, running (min1, min2, argmin)
    int k0 = kt * 64;
    #pragma unroll
    for (int j = 0; j < 4; ++j) {
      int kk = k0 + tx * 4 + j;
      float eq = esq[kk];
      #pragma unroll
      for (int i = 0; i < 4; ++i) {
        float dd = fmaf(-2.0f, accs[i][j], eq);
        if (dd < minv[i]) { min2[i] = minv[i]; minv[i] = dd; mini[i] = kk; }
        else if (dd < min2[i]) { min2[i] = dd; }
      }
    }
  }

  // reduce across the 16 tx lanes (same wave)
  #pragma unroll
  for (int s = 1; s < 16; s <<= 1) {
    #pragma unroll
    for (int i = 0; i < 4; ++i) {
      float ov = __shfl_xor(minv[i], s, 64);
      int   oi = __shfl_xor(mini[i], s, 64);
      float o2 = __shfl_xor(min2[i], s, 64);
      float big = fmaxf(minv[i], ov);
      float m2n = fminf(fminf(min2[i], o2), big);
      if (ov < minv[i] || (ov == minv[i] && oi < mini[i])) { minv[i] = ov; mini[i] = oi; }
      min2[i] = m2n;
    }
  }
  if (tx == 0) {
    #pragma unroll
    for (int i = 0; i < 4; ++i) {
      int row = row0 + ty * 4 + i;
      idxo[row] = mini[i];
      if (min2[i] - minv[i] < TAU) {
        int pos = atomicAdd(listc, 1);
        list[pos] = row;
      }
    }
  }
}

// ---------------- fp64 rescore of near-tie rows ----------------
// Block b owns K-slice [b*32, b*32+32), staged once in LDS; loops listed rows.
__global__ void k_rescore(const float* __restrict__ x, const float* __restrict__ emb,
                          const int* __restrict__ listc, const int* __restrict__ list,
                          unsigned long long* __restrict__ keys) {
  __shared__ float se[8192];     // [d][c] : d*32 + c
  __shared__ double red[256];    // [c][p] : c*8 + p
  const int t = threadIdx.x;
  const int k0 = blockIdx.x * 32;
  #pragma unroll
  for (int i = 0; i < 32; ++i) {
    int elem = i * 256 + t;
    int d = elem >> 5, c = elem & 31;
    se[d * 32 + c] = emb[(size_t)d * KK + k0 + c];
  }
  __syncthreads();
  const int c = t & 31, p = t >> 5;  // p in [0,8): 32 d's each
  int cnt = *listc;
  for (int li = 0; li < cnt; ++li) {
    int row = list[li];
    const float* xr = x + (size_t)row * DD;
    double acc = 0.0;
    #pragma unroll
    for (int j = 0; j < 32; ++j) {
      int d = p * 32 + j;
      double df = (double)xr[d] - (double)se[d * 32 + c];
      acc = fma(df, df, acc);
    }
    red[c * 8 + p] = acc;
    __syncthreads();
    if (t < 64) {
      unsigned long long key = ~0ull;
      if (t < 32) {
        double dist = 0.0;
        #pragma unroll
        for (int q = 0; q < 8; ++q) dist += red[t * 8 + q];
        key = ((unsigned long long)__double_as_longlong(dist) & ~0x1FFFull)
              | (unsigned long long)(k0 + t);
      }
      #pragma unroll
      for (int s = 1; s < 64; s <<= 1) {
        unsigned long long o = __shfl_xor(key, s, 64);
        if (o < key) key = o;
      }
      if (t == 0) atomicMin(&keys[row], key);
    }
    __syncthreads();
  }
}

__global__ void k_fixup(const int* __restrict__ listc, const int* __restrict__ list,
                        const unsigned long long* __restrict__ keys, int* __restrict__ idxw) {
  int cnt = *listc;
  for (int li = threadIdx.x; li < cnt; li += 256) {
    int row = list[li];
    idxw[row] = (int)(keys[row] & 0x1FFFull);
  }
}

// ---------------- gather + outputs + scatter stats ----------------
__global__ void k_gather(const float* __restrict__ x, const float* __restrict__ emb,
                         const int* __restrict__ idxw, const int* __restrict__ train,
                         float* __restrict__ outq, float* __restrict__ outidx,
                         float* __restrict__ out4, float* __restrict__ counts,
                         float* __restrict__ loss) {
  int n = blockIdx.x;
  int l = threadIdx.x; // 0..63
  int k = idxw[n];
  float4 xv = ((const float4*)(x + (size_t)n * DD))[l];
  int d = l * 4;
  float q0 = emb[(size_t)(d + 0) * KK + k];
  float q1 = emb[(size_t)(d + 1) * KK + k];
  float q2 = emb[(size_t)(d + 2) * KK + k];
  float q3 = emb[(size_t)(d + 3) * KK + k];

  float4 o;
  o.x = xv.x + (q0 - xv.x);
  o.y = xv.y + (q1 - xv.y);
  o.z = xv.z + (q2 - xv.z);
  o.w = xv.w + (q3 - xv.w);
  ((float4*)(outq + (size_t)n * DD))[l] = o;

  float e0 = q0 - xv.x, e1 = q1 - xv.y, e2 = q2 - xv.z, e3 = q3 - xv.w;
  float ls = (e0 * e0 + e1 * e1) + (e2 * e2 + e3 * e3);

  if (*train) {
    const float w = 1.0f - DECAYF;
    atomicAdd(&out4[(size_t)(d + 0) * KK + k], xv.x * w);
    atomicAdd(&out4[(size_t)(d + 1) * KK + k], xv.y * w);
    atomicAdd(&out4[(size_t)(d + 2) * KK + k], xv.z * w);
    atomicAdd(&out4[(size_t)(d + 3) * KK + k], xv.w * w);
  }

  #pragma unroll
  for (int m = 1; m < 64; m <<= 1) ls += __shfl_xor(ls, m, 64);
  if (l == 0) {
    atomicAdd(loss, ls);
    atomicAdd(&counts[k], 1.0f);
    outidx[n] = (float)k;
  }
}

// ---------------- EMA cluster stats, loss, perplexity ----------------
__global__ void k_stats(const float* __restrict__ counts, const float* __restrict__ ema_cs,
                        const int* __restrict__ counter, const int* __restrict__ train,
                        const float* __restrict__ loss, float* __restrict__ csn,
                        float* __restrict__ outloss, float* __restrict__ outperp) {
  __shared__ float s_n[4], s_e[4], s_tot[1];
  int tid = threadIdx.x;
  float debias = 1.0f - powf(DECAYF, (float)(*counter + 1));
  float nloc = 0.f, eloc = 0.f;
  float avg[32];
  for (int i = 0; i < 32; ++i) {
    int k = tid + i * 256;
    float c = counts[k];
    float h = ema_cs[k] * DECAYF + c * (1.0f - DECAYF);
    float a = h / debias;
    avg[i] = a;
    nloc += a;
    float p = c * (1.0f / 16384.0f);
    eloc += p * logf(p + 1e-10f);
  }
  #pragma unroll
  for (int m = 1; m < 64; m <<= 1) {
    nloc += __shfl_xor(nloc, m, 64);
    eloc += __shfl_xor(eloc, m, 64);
  }
  int w = tid >> 6, lane = tid & 63;
  if (lane == 0) { s_n[w] = nloc; s_e[w] = eloc; }
  __syncthreads();
  if (tid == 0) {
    float nt = (s_n[0] + s_n[1]) + (s_n[2] + s_n[3]);
    float et = (s_e[0] + s_e[1]) + (s_e[2] + s_e[3]);
    s_tot[0] = nt;
    outperp[0] = expf(-et);
    outloss[0] = 0.25f * (loss[0] / 4194304.0f);
  }
  __syncthreads();
  float nsum = s_tot[0];
  float denom = nsum + 8192.0f * EPSF;
  for (int i = 0; i < 32; ++i) {
    int k = tid + i * 256;
    csn[k] = (avg[i] + EPSF) / denom * nsum;
  }
}

// ---------------- finalize new_embeddings ----------------
__global__ void k_final(float* __restrict__ out4, const float* __restrict__ csn,
                        const int* __restrict__ counter, const int* __restrict__ train) {
  if (!*train) return;
  int i = blockIdx.x * 256 + threadIdx.x; // float2 index, 1048576 total
  float debias = 1.0f - powf(DECAYF, (float)(*counter + 1));
  float2 v = ((float2*)out4)[i];
  int k2 = i & 4095; // 4096 float2 per row of K=8192
  float2 c = ((const float2*)csn)[k2];
  v.x = (v.x / debias) / c.x;
  v.y = (v.y / debias) / c.y;
  ((float2*)out4)[i] = v;
}

extern "C" void kernel_launch(void* const* d_in, const int* in_sizes, int n_in,
                              void* d_out, int out_size, void* d_ws, size_t ws_size,
                              hipStream_t stream) {
  (void)in_sizes; (void)n_in; (void)out_size; (void)ws_size;
  const float* x      = (const float*)d_in[0];
  const float* emb    = (const float*)d_in[1];
  const float* ema_cs = (const float*)d_in[2];
  const float* ema_dw = (const float*)d_in[3];
  const int*   counter = (const int*)d_in[4];
  const int*   train   = (const int*)d_in[5];

  float* out = (float*)d_out;
  float* outq    = out + O_Q;
  float* outloss = out + O_LOSS;
  float* outperp = out + O_PERP;
  float* outidx  = out + O_IDX;
  float* out4    = out + O_EMB;

  float* ws     = (float*)d_ws;
  float* counts = ws + WS_COUNTS;
  float* loss   = ws + WS_LOSS;
  int*   listc  = (int*)(ws + WS_LISTC);
  int*   list   = (int*)(ws + WS_LIST);
  float* esq    = ws + WS_ESQ;
  float* csn    = ws + WS_CSN;
  int*   idxw   = (int*)(ws + WS_IDX);
  unsigned long long* keys = (unsigned long long*)(ws + WS_KEY);

  // zero counts (8192) + loss (1) + listc (1), contiguous; keys to +inf
  hipMemsetAsync(counts, 0, (KK + 2) * sizeof(float), stream);
  hipMemsetAsync(keys, 0xFF, NN * sizeof(unsigned long long), stream);

  k_colsq<<<KK / 256, 256, 0, stream>>>(emb, esq);
  k_init_emb<<<(DD * KK / 2) / 256, 256, 0, stream>>>(ema_dw, emb, train, out4);
  k_dist<<<NN / 64, 256, 0, stream>>>(x, emb, esq, idxw, listc, list);
  k_rescore<<<KK / 32, 256, 0, stream>>>(x, emb, listc, list, keys);
  k_fixup<<<1, 256, 0, stream>>>(listc, list, keys, idxw);
  k_gather<<<NN, 64, 0, stream>>>(x, emb, idxw, train, outq, outidx, out4, counts, loss);
  k_stats<<<1, 256, 0, stream>>>(counts, ema_cs, counter, train, loss, csn, outloss, outperp);
  k_final<<<(DD * KK / 2) / 256, 256, 0, stream>>>(out4, csn, counter, train);
}

// Round 3
// 684.158 us; speedup vs baseline: 3.4151x; 3.4151x over previous
//
#include <hip/hip_runtime.h>
#include <math.h>

#define DD 256
#define KK 8192
#define NN 16384
#define DECAYF 0.99f
#define EPSF 1e-5f
#define TAU 1e-3f

// output layout (floats)
#define O_Q    0
#define O_LOSS 4194304
#define O_PERP 4194305
#define O_IDX  4194306
#define O_EMB  4210690

typedef float f32x4 __attribute__((ext_vector_type(4)));
typedef __bf16 bf16x8 __attribute__((ext_vector_type(8)));

__device__ __forceinline__ unsigned short f2bf(float f) {
  unsigned int u = __float_as_uint(f);
  unsigned int r = (u + 0x7FFFu + ((u >> 16) & 1u)) >> 16;
  return (unsigned short)r;
}
__device__ __forceinline__ float bf2f(unsigned short h) {
  return __uint_as_float(((unsigned int)h) << 16);
}

__device__ __forceinline__ void gll16(const void* g, void* l) {
  __builtin_amdgcn_global_load_lds((const __attribute__((address_space(1))) void*)g,
                                   (__attribute__((address_space(3))) void*)l, 16, 0, 0);
}

// ---------------- split x into bf16 hi/lo [N,D] ----------------
__global__ void k_convert_x(const float* __restrict__ x, unsigned short* __restrict__ hi,
                            unsigned short* __restrict__ lo) {
  int i = blockIdx.x * 256 + threadIdx.x; // float4 index, 1048576 total
  float4 v = ((const float4*)x)[i];
  ushort4 hv, lv;
  hv.x = f2bf(v.x); hv.y = f2bf(v.y); hv.z = f2bf(v.z); hv.w = f2bf(v.w);
  lv.x = f2bf(v.x - bf2f(hv.x)); lv.y = f2bf(v.y - bf2f(hv.y));
  lv.z = f2bf(v.z - bf2f(hv.z)); lv.w = f2bf(v.w - bf2f(hv.w));
  ((ushort4*)hi)[i] = hv;
  ((ushort4*)lo)[i] = lv;
}

// ---------------- transpose emb [D,K] -> embT [K,D] fp32 + bf16 hi/lo -------
__global__ void k_convert_e(const float* __restrict__ emb, unsigned short* __restrict__ bthi,
                            unsigned short* __restrict__ btlo, float* __restrict__ embT) {
  __shared__ float ld[32 * 33];
  int t = threadIdx.x;
  int k0 = blockIdx.x * 32, d0 = blockIdx.y * 32;
  {
    int din = t >> 3, kq = (t & 7) * 4;
    float4 v = *(const float4*)(emb + (size_t)(d0 + din) * KK + k0 + kq);
    ld[din * 33 + kq + 0] = v.x; ld[din * 33 + kq + 1] = v.y;
    ld[din * 33 + kq + 2] = v.z; ld[din * 33 + kq + 3] = v.w;
  }
  __syncthreads();
  int kout = t >> 3, dq = (t & 7) * 4;
  float f0 = ld[(dq + 0) * 33 + kout], f1 = ld[(dq + 1) * 33 + kout];
  float f2 = ld[(dq + 2) * 33 + kout], f3 = ld[(dq + 3) * 33 + kout];
  size_t o = (size_t)(k0 + kout) * DD + d0 + dq;
  float4 fv; fv.x = f0; fv.y = f1; fv.z = f2; fv.w = f3;
  *(float4*)(embT + o) = fv;
  ushort4 hv, lv;
  hv.x = f2bf(f0); hv.y = f2bf(f1); hv.z = f2bf(f2); hv.w = f2bf(f3);
  lv.x = f2bf(f0 - bf2f(hv.x)); lv.y = f2bf(f1 - bf2f(hv.y));
  lv.z = f2bf(f2 - bf2f(hv.z)); lv.w = f2bf(f3 - bf2f(hv.w));
  *(ushort4*)(bthi + o) = hv;
  *(ushort4*)(btlo + o) = lv;
}

// ---------------- column squared norms of embeddings (fp64) ----------------
__global__ void k_colsq(const float* __restrict__ emb, float* __restrict__ esq) {
  __shared__ double red[256];
  int t = threadIdx.x;
  int k = blockIdx.x * 32 + (t & 31);
  int p = t >> 5;
  double s = 0.0;
  for (int j = 0; j < 32; ++j) {
    int d = p * 32 + j;
    double v = (double)emb[(size_t)d * KK + k];
    s = fma(v, v, s);
  }
  red[p * 32 + (t & 31)] = s;
  __syncthreads();
  if (t < 32) {
    double tot = 0.0;
    #pragma unroll
    for (int pp = 0; pp < 8; ++pp) tot += red[pp * 32 + t];
    esq[blockIdx.x * 32 + t] = (float)tot;
  }
}

// ---------------- init new_embeddings output ----------------
__global__ void k_init_emb(const float* __restrict__ ema_dw, const float* __restrict__ emb,
                           const int* __restrict__ train, float* __restrict__ out4) {
  int i = blockIdx.x * 256 + threadIdx.x; // float2 index, 1048576 total
  int tr = *train;
  const float2* src = tr ? (const float2*)ema_dw : (const float2*)emb;
  float2 v = src[i];
  if (tr) { v.x *= DECAYF; v.y *= DECAYF; }
  ((float2*)out4)[i] = v;
}

// ---------------- MFMA distance screening ----------------
// grid (64 kb, 128 nb); block 256 threads = 4 waves; tile 128 rows x 128 cols.
// dd = esq[k] - 2*(xhi.ehi + xhi.elo + xlo.ehi); per-(row,kb) partial
// (min1,min2,argmin) written to ws. Wave w owns rows [w*32, w*32+32), all 128 cols.
__launch_bounds__(256, 2)
__global__ void k_dist_mfma(const unsigned short* __restrict__ Ahi, const unsigned short* __restrict__ Alo,
                            const unsigned short* __restrict__ Bhi, const unsigned short* __restrict__ Blo,
                            const float* __restrict__ esq,
                            float* __restrict__ part1, float* __restrict__ part2,
                            int* __restrict__ partidx) {
  __shared__ __align__(16) unsigned short smem[4 * 4096]; // Ahi|Alo|Bhi|Blo 128x32 each
  unsigned short* sAhi = smem;
  unsigned short* sAlo = smem + 4096;
  unsigned short* sBhi = smem + 8192;
  unsigned short* sBlo = smem + 12288;

  const int tid = threadIdx.x;
  const int w = tid >> 6, lane = tid & 63;
  const int kb = blockIdx.x, nb = blockIdx.y;
  const int row0 = nb * 128, col0 = kb * 128;

  // --- staging addresses: wave w stages rows/cols [w*32, w*32+32), 2 chunks of 16
  const int rs0 = w * 32 + (lane >> 2);
  const int rs1 = rs0 + 16;
  const int sl = lane & 3;
  const int c0 = sl ^ ((rs0 >> 1) & 3);
  const int c1 = sl ^ ((rs1 >> 1) & 3);
  const size_t gA0 = (size_t)(row0 + rs0) * DD + c0 * 8;
  const size_t gA1 = (size_t)(row0 + rs1) * DD + c1 * 8;
  const size_t gB0 = (size_t)(col0 + rs0) * DD + c0 * 8;
  const size_t gB1 = (size_t)(col0 + rs1) * DD + c1 * 8;
  const int l0 = (w * 32) * 32;        // lds element base, chunk 0
  const int l1 = (w * 32 + 16) * 32;   // chunk 1

  // --- frag read addresses
  const int m = lane & 15, q = lane >> 4;
  const int slot = q ^ ((m >> 1) & 3);
  const int wrow0 = w * 32;
  const int aoff = (wrow0 + m) * 32 + slot * 8;  // + i*512
  const int boff = m * 32 + slot * 8;            // + j*512

  f32x4 acc[2][8];
  #pragma unroll
  for (int i = 0; i < 2; ++i)
    #pragma unroll
    for (int j = 0; j < 8; ++j) acc[i][j] = (f32x4)0.f;

  for (int dt = 0; dt < 8; ++dt) {
    const int d0 = dt * 32;
    __syncthreads();
    gll16(Ahi + gA0 + d0, sAhi + l0);
    gll16(Ahi + gA1 + d0, sAhi + l1);
    gll16(Alo + gA0 + d0, sAlo + l0);
    gll16(Alo + gA1 + d0, sAlo + l1);
    gll16(Bhi + gB0 + d0, sBhi + l0);
    gll16(Bhi + gB1 + d0, sBhi + l1);
    gll16(Blo + gB0 + d0, sBlo + l0);
    gll16(Blo + gB1 + d0, sBlo + l1);
    __syncthreads();

    bf16x8 ah[2], al[2];
    #pragma unroll
    for (int i = 0; i < 2; ++i) {
      ah[i] = *(const bf16x8*)(sAhi + aoff + i * 512);
      al[i] = *(const bf16x8*)(sAlo + aoff + i * 512);
    }
    #pragma unroll
    for (int j = 0; j < 8; ++j) {
      bf16x8 bh = *(const bf16x8*)(sBhi + boff + j * 512);
      bf16x8 bl = *(const bf16x8*)(sBlo + boff + j * 512);
      #pragma unroll
      for (int i = 0; i < 2; ++i) {
        acc[i][j] = __builtin_amdgcn_mfma_f32_16x16x32_bf16(ah[i], bh, acc[i][j], 0, 0, 0);
        acc[i][j] = __builtin_amdgcn_mfma_f32_16x16x32_bf16(ah[i], bl, acc[i][j], 0, 0, 0);
        acc[i][j] = __builtin_amdgcn_mfma_f32_16x16x32_bf16(al[i], bh, acc[i][j], 0, 0, 0);
      }
    }
  }

  // --- epilogue: dd = esq - 2*dot, (min1,min2,argmin) per row over 128 cols
  float eq[8];
  #pragma unroll
  for (int j = 0; j < 8; ++j) eq[j] = esq[col0 + j * 16 + m];

  #pragma unroll
  for (int i = 0; i < 2; ++i) {
    #pragma unroll
    for (int reg = 0; reg < 4; ++reg) {
      float m1 = 3.402823466e+38f, m2 = 3.402823466e+38f;
      int bi = 0;
      #pragma unroll
      for (int j = 0; j < 8; ++j) {
        float dd = fmaf(-2.0f, acc[i][j][reg], eq[j]);
        if (dd < m1) { m2 = m1; m1 = dd; bi = col0 + j * 16 + m; }
        else if (dd < m2) m2 = dd;
      }
      #pragma unroll
      for (int st = 1; st < 16; st <<= 1) {
        float ov = __shfl_xor(m1, st, 64);
        int   oi = __shfl_xor(bi, st, 64);
        float o2 = __shfl_xor(m2, st, 64);
        float big = fmaxf(m1, ov);
        m2 = fminf(fminf(m2, o2), big);
        if (ov < m1 || (ov == m1 && oi < bi)) { m1 = ov; bi = oi; }
      }
      if (m == 0) {
        int prow = row0 + wrow0 + i * 16 + q * 4 + reg;
        int pidx = prow * 64 + kb;
        part1[pidx] = m1; part2[pidx] = m2; partidx[pidx] = bi;
      }
    }
  }
}

// ---------------- reduce 64 k-block partials per row ----------------
__global__ void k_argmin2(const float* __restrict__ part1, const float* __restrict__ part2,
                          const int* __restrict__ partidx, int* __restrict__ idxw,
                          int* __restrict__ listc, int* __restrict__ list) {
  int w = threadIdx.x >> 6, l = threadIdx.x & 63;
  int row = blockIdx.x * 4 + w;
  int base = row * 64 + l;
  float m1 = part1[base], m2 = part2[base];
  int bi = partidx[base];
  #pragma unroll
  for (int st = 1; st < 64; st <<= 1) {
    float ov = __shfl_xor(m1, st, 64);
    int   oi = __shfl_xor(bi, st, 64);
    float o2 = __shfl_xor(m2, st, 64);
    float big = fmaxf(m1, ov);
    m2 = fminf(fminf(m2, o2), big);
    if (ov < m1 || (ov == m1 && oi < bi)) { m1 = ov; bi = oi; }
  }
  if (l == 0) {
    idxw[row] = bi;
    if (m2 - m1 < TAU) { int pos = atomicAdd(listc, 1); list[pos] = row; }
  }
}

// ---------------- fp64 rescore of near-tie rows ----------------
__global__ void k_rescore(const float* __restrict__ x, const float* __restrict__ emb,
                          const int* __restrict__ listc, const int* __restrict__ list,
                          unsigned long long* __restrict__ keys) {
  __shared__ float se[8192];     // [d][c]
  __shared__ double red[256];
  const int t = threadIdx.x;
  const int k0 = blockIdx.x * 32;
  #pragma unroll
  for (int i = 0; i < 32; ++i) {
    int elem = i * 256 + t;
    int d = elem >> 5, c = elem & 31;
    se[d * 32 + c] = emb[(size_t)d * KK + k0 + c];
  }
  __syncthreads();
  const int c = t & 31, p = t >> 5;
  int cnt = *listc;
  for (int li = 0; li < cnt; ++li) {
    int row = list[li];
    const float* xr = x + (size_t)row * DD;
    double acc = 0.0;
    #pragma unroll
    for (int j = 0; j < 32; ++j) {
      int d = p * 32 + j;
      double df = (double)xr[d] - (double)se[d * 32 + c];
      acc = fma(df, df, acc);
    }
    red[c * 8 + p] = acc;
    __syncthreads();
    if (t < 64) {
      unsigned long long key = ~0ull;
      if (t < 32) {
        double dist = 0.0;
        #pragma unroll
        for (int qq = 0; qq < 8; ++qq) dist += red[t * 8 + qq];
        key = ((unsigned long long)__double_as_longlong(dist) & ~0x1FFFull)
              | (unsigned long long)(k0 + t);
      }
      #pragma unroll
      for (int s = 1; s < 64; s <<= 1) {
        unsigned long long o = __shfl_xor(key, s, 64);
        if (o < key) key = o;
      }
      if (t == 0) atomicMin(&keys[row], key);
    }
    __syncthreads();
  }
}

__global__ void k_fixup(const int* __restrict__ listc, const int* __restrict__ list,
                        const unsigned long long* __restrict__ keys, int* __restrict__ idxw) {
  int cnt = *listc;
  for (int li = threadIdx.x; li < cnt; li += 256) {
    int row = list[li];
    idxw[row] = (int)(keys[row] & 0x1FFFull);
  }
}

// ---------------- gather + outputs + scatter stats (coalesced via embT) -----
__global__ void k_gather(const float* __restrict__ x, const float* __restrict__ embT,
                         const int* __restrict__ idxw, const int* __restrict__ train,
                         float* __restrict__ outq, float* __restrict__ outidx,
                         float* __restrict__ out4, float* __restrict__ counts,
                         float* __restrict__ loss) {
  int n = blockIdx.x;
  int l = threadIdx.x; // 0..63
  int k = idxw[n];
  float4 xv = ((const float4*)(x + (size_t)n * DD))[l];
  float4 qv = ((const float4*)(embT + (size_t)k * DD))[l];
  int d = l * 4;

  ((float4*)(outq + (size_t)n * DD))[l] = qv; // x + (q - x) == q

  float e0 = qv.x - xv.x, e1 = qv.y - xv.y, e2 = qv.z - xv.z, e3 = qv.w - xv.w;
  float ls = (e0 * e0 + e1 * e1) + (e2 * e2 + e3 * e3);

  if (*train) {
    const float wdw = 1.0f - DECAYF;
    atomicAdd(&out4[(size_t)(d + 0) * KK + k], xv.x * wdw);
    atomicAdd(&out4[(size_t)(d + 1) * KK + k], xv.y * wdw);
    atomicAdd(&out4[(size_t)(d + 2) * KK + k], xv.z * wdw);
    atomicAdd(&out4[(size_t)(d + 3) * KK + k], xv.w * wdw);
  }

  #pragma unroll
  for (int s = 1; s < 64; s <<= 1) ls += __shfl_xor(ls, s, 64);
  if (l == 0) {
    atomicAdd(loss, ls);
    atomicAdd(&counts[k], 1.0f);
    outidx[n] = (float)k;
  }
}

// ---------------- EMA cluster stats, loss, perplexity ----------------
__global__ void k_stats(const float* __restrict__ counts, const float* __restrict__ ema_cs,
                        const int* __restrict__ counter, const int* __restrict__ train,
                        const float* __restrict__ loss, float* __restrict__ csn,
                        float* __restrict__ outloss, float* __restrict__ outperp) {
  __shared__ float s_n[4], s_e[4], s_tot[1];
  int tid = threadIdx.x;
  float debias = 1.0f - powf(DECAYF, (float)(*counter + 1));
  float nloc = 0.f, eloc = 0.f;
  float avg[32];
  for (int i = 0; i < 32; ++i) {
    int k = tid + i * 256;
    float c = counts[k];
    float h = ema_cs[k] * DECAYF + c * (1.0f - DECAYF);
    float a = h / debias;
    avg[i] = a;
    nloc += a;
    float p = c * (1.0f / 16384.0f);
    eloc += p * logf(p + 1e-10f);
  }
  #pragma unroll
  for (int s = 1; s < 64; s <<= 1) {
    nloc += __shfl_xor(nloc, s, 64);
    eloc += __shfl_xor(eloc, s, 64);
  }
  int w = tid >> 6, lane = tid & 63;
  if (lane == 0) { s_n[w] = nloc; s_e[w] = eloc; }
  __syncthreads();
  if (tid == 0) {
    float nt = (s_n[0] + s_n[1]) + (s_n[2] + s_n[3]);
    float et = (s_e[0] + s_e[1]) + (s_e[2] + s_e[3]);
    s_tot[0] = nt;
    outperp[0] = expf(-et);
    outloss[0] = 0.25f * (loss[0] / 4194304.0f);
  }
  __syncthreads();
  float nsum = s_tot[0];
  float denom = nsum + 8192.0f * EPSF;
  for (int i = 0; i < 32; ++i) {
    int k = tid + i * 256;
    csn[k] = (avg[i] + EPSF) / denom * nsum;
  }
}

// ---------------- finalize new_embeddings ----------------
__global__ void k_final(float* __restrict__ out4, const float* __restrict__ csn,
                        const int* __restrict__ counter, const int* __restrict__ train) {
  if (!*train) return;
  int i = blockIdx.x * 256 + threadIdx.x; // float2 index, 1048576 total
  float debias = 1.0f - powf(DECAYF, (float)(*counter + 1));
  float2 v = ((float2*)out4)[i];
  int k2 = i & 4095;
  float2 c = ((const float2*)csn)[k2];
  v.x = (v.x / debias) / c.x;
  v.y = (v.y / debias) / c.y;
  ((float2*)out4)[i] = v;
}

extern "C" void kernel_launch(void* const* d_in, const int* in_sizes, int n_in,
                              void* d_out, int out_size, void* d_ws, size_t ws_size,
                              hipStream_t stream) {
  (void)in_sizes; (void)n_in; (void)out_size; (void)ws_size;
  const float* x      = (const float*)d_in[0];
  const float* emb    = (const float*)d_in[1];
  const float* ema_cs = (const float*)d_in[2];
  const float* ema_dw = (const float*)d_in[3];
  const int*   counter = (const int*)d_in[4];
  const int*   train   = (const int*)d_in[5];

  float* out = (float*)d_out;
  float* outq    = out + O_Q;
  float* outloss = out + O_LOSS;
  float* outperp = out + O_PERP;
  float* outidx  = out + O_IDX;
  float* out4    = out + O_EMB;

  // workspace carve (bytes)
  char* W = (char*)d_ws;
  unsigned short* Ahi  = (unsigned short*)(W);              //  8 MB
  unsigned short* Alo  = (unsigned short*)(W + 8388608);    //  8 MB
  unsigned short* BThi = (unsigned short*)(W + 16777216);   //  4 MB
  unsigned short* BTlo = (unsigned short*)(W + 20971520);   //  4 MB
  float* embT          = (float*)(W + 25165824);            //  8 MB
  float* part1         = (float*)(W + 33554432);            //  4 MB
  float* part2         = (float*)(W + 37748736);            //  4 MB
  int*   partidx       = (int*)(W + 41943040);              //  4 MB
  unsigned long long* keys = (unsigned long long*)(W + 46137344); // 128 KB
  float* esq           = (float*)(W + 46268416);
  float* csn           = (float*)(W + 46301184);
  float* counts        = (float*)(W + 46333952);
  float* loss          = (float*)(W + 46366720);
  int*   listc         = (int*)(W + 46366724);
  int*   list          = (int*)(W + 46366728);
  int*   idxw          = (int*)(W + 46432264);

  hipMemsetAsync(counts, 0, 32768 + 8, stream);              // counts + loss + listc
  hipMemsetAsync(keys, 0xFF, NN * sizeof(unsigned long long), stream);

  k_convert_x<<<4096, 256, 0, stream>>>(x, Ahi, Alo);
  k_convert_e<<<dim3(256, 8), 256, 0, stream>>>(emb, BThi, BTlo, embT);
  k_colsq<<<256, 256, 0, stream>>>(emb, esq);
  k_init_emb<<<4096, 256, 0, stream>>>(ema_dw, emb, train, out4);
  k_dist_mfma<<<dim3(64, 128), 256, 0, stream>>>(Ahi, Alo, BThi, BTlo, esq, part1, part2, partidx);
  k_argmin2<<<4096, 256, 0, stream>>>(part1, part2, partidx, idxw, listc, list);
  k_rescore<<<256, 256, 0, stream>>>(x, emb, listc, list, keys);
  k_fixup<<<1, 256, 0, stream>>>(listc, list, keys, idxw);
  k_gather<<<NN, 64, 0, stream>>>(x, embT, idxw, train, outq, outidx, out4, counts, loss);
  k_stats<<<1, 256, 0, stream>>>(counts, ema_cs, counter, train, loss, csn, outloss, outperp);
  k_final<<<4096, 256, 0, stream>>>(out4, csn, counter, train);
}

// Round 7
// 466.843 us; speedup vs baseline: 5.0048x; 1.4655x over previous
//
#include <hip/hip_runtime.h>
#include <math.h>

#define DD 256
#define KK 8192
#define NN 16384
#define DECAYF 0.99f
#define EPSF 1e-5f
#define TAU 1e-3f

// output layout (floats)
#define O_Q    0
#define O_LOSS 4194304
#define O_PERP 4194305
#define O_IDX  4194306
#define O_EMB  4210690

typedef float f32x4 __attribute__((ext_vector_type(4)));
typedef __bf16 bf16x8 __attribute__((ext_vector_type(8)));

__device__ __forceinline__ unsigned short f2bf(float f) {
  unsigned int u = __float_as_uint(f);
  unsigned int r = (u + 0x7FFFu + ((u >> 16) & 1u)) >> 16;
  return (unsigned short)r;
}
__device__ __forceinline__ float bf2f(unsigned short h) {
  return __uint_as_float(((unsigned int)h) << 16);
}

__device__ __forceinline__ void gll16(const void* g, void* l) {
  __builtin_amdgcn_global_load_lds((const __attribute__((address_space(1))) void*)g,
                                   (__attribute__((address_space(3))) void*)l, 16, 0, 0);
}

// ---------------- split x into bf16 hi/lo [N,D] ----------------
__global__ void k_convert_x(const float* __restrict__ x, unsigned short* __restrict__ hi,
                            unsigned short* __restrict__ lo) {
  int i = blockIdx.x * 256 + threadIdx.x; // float4 index, 1048576 total
  float4 v = ((const float4*)x)[i];
  ushort4 hv, lv;
  hv.x = f2bf(v.x); hv.y = f2bf(v.y); hv.z = f2bf(v.z); hv.w = f2bf(v.w);
  lv.x = f2bf(v.x - bf2f(hv.x)); lv.y = f2bf(v.y - bf2f(hv.y));
  lv.z = f2bf(v.z - bf2f(hv.z)); lv.w = f2bf(v.w - bf2f(hv.w));
  ((ushort4*)hi)[i] = hv;
  ((ushort4*)lo)[i] = lv;
}

// ---------------- transpose emb [D,K] -> embT [K,D] fp32 + bf16 hi/lo -------
__global__ void k_convert_e(const float* __restrict__ emb, unsigned short* __restrict__ bthi,
                            unsigned short* __restrict__ btlo, float* __restrict__ embT) {
  __shared__ float ld[32 * 33];
  int t = threadIdx.x;
  int k0 = blockIdx.x * 32, d0 = blockIdx.y * 32;
  {
    int din = t >> 3, kq = (t & 7) * 4;
    float4 v = *(const float4*)(emb + (size_t)(d0 + din) * KK + k0 + kq);
    ld[din * 33 + kq + 0] = v.x; ld[din * 33 + kq + 1] = v.y;
    ld[din * 33 + kq + 2] = v.z; ld[din * 33 + kq + 3] = v.w;
  }
  __syncthreads();
  int kout = t >> 3, dq = (t & 7) * 4;
  float f0 = ld[(dq + 0) * 33 + kout], f1 = ld[(dq + 1) * 33 + kout];
  float f2 = ld[(dq + 2) * 33 + kout], f3 = ld[(dq + 3) * 33 + kout];
  size_t o = (size_t)(k0 + kout) * DD + d0 + dq;
  float4 fv; fv.x = f0; fv.y = f1; fv.z = f2; fv.w = f3;
  *(float4*)(embT + o) = fv;
  ushort4 hv, lv;
  hv.x = f2bf(f0); hv.y = f2bf(f1); hv.z = f2bf(f2); hv.w = f2bf(f3);
  lv.x = f2bf(f0 - bf2f(hv.x)); lv.y = f2bf(f1 - bf2f(hv.y));
  lv.z = f2bf(f2 - bf2f(hv.z)); lv.w = f2bf(f3 - bf2f(hv.w));
  *(ushort4*)(bthi + o) = hv;
  *(ushort4*)(btlo + o) = lv;
}

// ---------------- column squared norms of embeddings (fp64) ----------------
__global__ void k_colsq(const float* __restrict__ emb, float* __restrict__ esq) {
  __shared__ double red[256];
  int t = threadIdx.x;
  int k = blockIdx.x * 32 + (t & 31);
  int p = t >> 5;
  double s = 0.0;
  for (int j = 0; j < 32; ++j) {
    int d = p * 32 + j;
    double v = (double)emb[(size_t)d * KK + k];
    s = fma(v, v, s);
  }
  red[p * 32 + (t & 31)] = s;
  __syncthreads();
  if (t < 32) {
    double tot = 0.0;
    #pragma unroll
    for (int pp = 0; pp < 8; ++pp) tot += red[pp * 32 + t];
    esq[blockIdx.x * 32 + t] = (float)tot;
  }
}

// ---------------- zero dwT: 8 MB = 2048 blocks x 256 threads x 16 B --------
// (round-6 bug: 8192 blocks wrote 32 MB, clobbering idxw/list/keys/counts)
__global__ void k_zero(float4* __restrict__ p) {
  p[(size_t)blockIdx.x * 256 + threadIdx.x] = make_float4(0.f, 0.f, 0.f, 0.f);
}

// ---------------- MFMA distance screening ----------------
// grid (64 kb, 128 nb); block 256 threads = 4 waves; tile 128 rows x 128 cols.
__launch_bounds__(256, 2)
__global__ void k_dist_mfma(const unsigned short* __restrict__ Ahi, const unsigned short* __restrict__ Alo,
                            const unsigned short* __restrict__ Bhi, const unsigned short* __restrict__ Blo,
                            const float* __restrict__ esq,
                            float* __restrict__ part1, float* __restrict__ part2,
                            int* __restrict__ partidx) {
  __shared__ __align__(16) unsigned short smem[4 * 4096]; // Ahi|Alo|Bhi|Blo 128x32 each
  unsigned short* sAhi = smem;
  unsigned short* sAlo = smem + 4096;
  unsigned short* sBhi = smem + 8192;
  unsigned short* sBlo = smem + 12288;

  const int tid = threadIdx.x;
  const int w = tid >> 6, lane = tid & 63;
  const int kb = blockIdx.x, nb = blockIdx.y;
  const int row0 = nb * 128, col0 = kb * 128;

  const int rs0 = w * 32 + (lane >> 2);
  const int rs1 = rs0 + 16;
  const int sl = lane & 3;
  const int c0 = sl ^ ((rs0 >> 1) & 3);
  const int c1 = sl ^ ((rs1 >> 1) & 3);
  const size_t gA0 = (size_t)(row0 + rs0) * DD + c0 * 8;
  const size_t gA1 = (size_t)(row0 + rs1) * DD + c1 * 8;
  const size_t gB0 = (size_t)(col0 + rs0) * DD + c0 * 8;
  const size_t gB1 = (size_t)(col0 + rs1) * DD + c1 * 8;
  const int l0 = (w * 32) * 32;
  const int l1 = (w * 32 + 16) * 32;

  const int m = lane & 15, q = lane >> 4;
  const int slot = q ^ ((m >> 1) & 3);
  const int wrow0 = w * 32;
  const int aoff = (wrow0 + m) * 32 + slot * 8;
  const int boff = m * 32 + slot * 8;

  f32x4 acc[2][8];
  #pragma unroll
  for (int i = 0; i < 2; ++i)
    #pragma unroll
    for (int j = 0; j < 8; ++j) acc[i][j] = (f32x4)0.f;

  for (int dt = 0; dt < 8; ++dt) {
    const int d0 = dt * 32;
    __syncthreads();
    gll16(Ahi + gA0 + d0, sAhi + l0);
    gll16(Ahi + gA1 + d0, sAhi + l1);
    gll16(Alo + gA0 + d0, sAlo + l0);
    gll16(Alo + gA1 + d0, sAlo + l1);
    gll16(Bhi + gB0 + d0, sBhi + l0);
    gll16(Bhi + gB1 + d0, sBhi + l1);
    gll16(Blo + gB0 + d0, sBlo + l0);
    gll16(Blo + gB1 + d0, sBlo + l1);
    __syncthreads();

    bf16x8 ah[2], al[2];
    #pragma unroll
    for (int i = 0; i < 2; ++i) {
      ah[i] = *(const bf16x8*)(sAhi + aoff + i * 512);
      al[i] = *(const bf16x8*)(sAlo + aoff + i * 512);
    }
    #pragma unroll
    for (int j = 0; j < 8; ++j) {
      bf16x8 bh = *(const bf16x8*)(sBhi + boff + j * 512);
      bf16x8 bl = *(const bf16x8*)(sBlo + boff + j * 512);
      #pragma unroll
      for (int i = 0; i < 2; ++i) {
        acc[i][j] = __builtin_amdgcn_mfma_f32_16x16x32_bf16(ah[i], bh, acc[i][j], 0, 0, 0);
        acc[i][j] = __builtin_amdgcn_mfma_f32_16x16x32_bf16(ah[i], bl, acc[i][j], 0, 0, 0);
        acc[i][j] = __builtin_amdgcn_mfma_f32_16x16x32_bf16(al[i], bh, acc[i][j], 0, 0, 0);
      }
    }
  }

  float eq[8];
  #pragma unroll
  for (int j = 0; j < 8; ++j) eq[j] = esq[col0 + j * 16 + m];

  #pragma unroll
  for (int i = 0; i < 2; ++i) {
    #pragma unroll
    for (int reg = 0; reg < 4; ++reg) {
      float m1 = 3.402823466e+38f, m2 = 3.402823466e+38f;
      int bi = 0;
      #pragma unroll
      for (int j = 0; j < 8; ++j) {
        float dd = fmaf(-2.0f, acc[i][j][reg], eq[j]);
        if (dd < m1) { m2 = m1; m1 = dd; bi = col0 + j * 16 + m; }
        else if (dd < m2) m2 = dd;
      }
      #pragma unroll
      for (int st = 1; st < 16; st <<= 1) {
        float ov = __shfl_xor(m1, st, 64);
        int   oi = __shfl_xor(bi, st, 64);
        float o2 = __shfl_xor(m2, st, 64);
        float big = fmaxf(m1, ov);
        m2 = fminf(fminf(m2, o2), big);
        if (ov < m1 || (ov == m1 && oi < bi)) { m1 = ov; bi = oi; }
      }
      if (m == 0) {
        int prow = row0 + wrow0 + i * 16 + q * 4 + reg;
        int pidx = prow * 64 + kb;
        part1[pidx] = m1; part2[pidx] = m2; partidx[pidx] = bi;
      }
    }
  }
}

// ---------------- reduce 64 k-block partials per row ----------------
__global__ void k_argmin2(const float* __restrict__ part1, const float* __restrict__ part2,
                          const int* __restrict__ partidx, int* __restrict__ idxw,
                          int* __restrict__ listc, int* __restrict__ list) {
  int w = threadIdx.x >> 6, l = threadIdx.x & 63;
  int row = blockIdx.x * 4 + w;
  int base = row * 64 + l;
  float m1 = part1[base], m2 = part2[base];
  int bi = partidx[base];
  #pragma unroll
  for (int st = 1; st < 64; st <<= 1) {
    float ov = __shfl_xor(m1, st, 64);
    int   oi = __shfl_xor(bi, st, 64);
    float o2 = __shfl_xor(m2, st, 64);
    float big = fmaxf(m1, ov);
    m2 = fminf(fminf(m2, o2), big);
    if (ov < m1 || (ov == m1 && oi < bi)) { m1 = ov; bi = oi; }
  }
  if (l == 0) {
    idxw[row] = bi;
    if (m2 - m1 < TAU) { int pos = atomicAdd(listc, 1); list[pos] = row; }
  }
}

// ---------------- fp64 rescore of near-tie rows ----------------
__global__ void k_rescore(const float* __restrict__ x, const float* __restrict__ emb,
                          const int* __restrict__ listc, const int* __restrict__ list,
                          unsigned long long* __restrict__ keys) {
  __shared__ float se[8192];
  __shared__ double red[256];
  const int t = threadIdx.x;
  const int k0 = blockIdx.x * 32;
  #pragma unroll
  for (int i = 0; i < 32; ++i) {
    int elem = i * 256 + t;
    int d = elem >> 5, c = elem & 31;
    se[d * 32 + c] = emb[(size_t)d * KK + k0 + c];
  }
  __syncthreads();
  const int c = t & 31, p = t >> 5;
  int cnt = *listc;
  for (int li = 0; li < cnt; ++li) {
    int row = list[li];
    const float* xr = x + (size_t)row * DD;
    double acc = 0.0;
    #pragma unroll
    for (int j = 0; j < 32; ++j) {
      int d = p * 32 + j;
      double df = (double)xr[d] - (double)se[d * 32 + c];
      acc = fma(df, df, acc);
    }
    red[c * 8 + p] = acc;
    __syncthreads();
    if (t < 64) {
      unsigned long long key = ~0ull;
      if (t < 32) {
        double dist = 0.0;
        #pragma unroll
        for (int qq = 0; qq < 8; ++qq) dist += red[t * 8 + qq];
        key = ((unsigned long long)__double_as_longlong(dist) & ~0x1FFFull)
              | (unsigned long long)(k0 + t);
      }
      #pragma unroll
      for (int s = 1; s < 64; s <<= 1) {
        unsigned long long o = __shfl_xor(key, s, 64);
        if (o < key) key = o;
      }
      if (t == 0) atomicMin(&keys[row], key);
    }
    __syncthreads();
  }
}

__global__ void k_fixup(const int* __restrict__ listc, const int* __restrict__ list,
                        const unsigned long long* __restrict__ keys, int* __restrict__ idxw) {
  int cnt = *listc;
  for (int li = threadIdx.x; li < cnt; li += 256) {
    int row = list[li];
    idxw[row] = (int)(keys[row] & 0x1FFFull);
  }
}

// ---------------- gather + outputs + scatter stats ----------------
// 256 threads = 4 rows per block. dw scatter goes into dwT [K,D] so each
// row's 256 adds are contiguous (16 cachelines) instead of 256 lines in [D,K].
__global__ void k_gather(const float* __restrict__ x, const float* __restrict__ embT,
                         const int* __restrict__ idxw, const int* __restrict__ train,
                         float* __restrict__ outq, float* __restrict__ outidx,
                         float* __restrict__ dwT, float* __restrict__ counts,
                         float* __restrict__ loss_part) {
  int w = threadIdx.x >> 6, l = threadIdx.x & 63;
  int n = blockIdx.x * 4 + w;
  int k = idxw[n];
  float4 xv = ((const float4*)(x + (size_t)n * DD))[l];
  float4 qv = ((const float4*)(embT + (size_t)k * DD))[l];
  int d = l * 4;

  ((float4*)(outq + (size_t)n * DD))[l] = qv; // x + (q - x) == q

  float e0 = qv.x - xv.x, e1 = qv.y - xv.y, e2 = qv.z - xv.z, e3 = qv.w - xv.w;
  float ls = (e0 * e0 + e1 * e1) + (e2 * e2 + e3 * e3);

  if (*train) {
    const float wdw = 1.0f - DECAYF;
    float* base = dwT + (size_t)k * DD + d;
    atomicAdd(base + 0, xv.x * wdw);
    atomicAdd(base + 1, xv.y * wdw);
    atomicAdd(base + 2, xv.z * wdw);
    atomicAdd(base + 3, xv.w * wdw);
  }

  #pragma unroll
  for (int s = 1; s < 64; s <<= 1) ls += __shfl_xor(ls, s, 64);
  if (l == 0) {
    atomicAdd(&loss_part[blockIdx.x & 255], ls);
    atomicAdd(&counts[k], 1.0f);
    outidx[n] = (float)k;
  }
}

// ---------------- EMA cluster stats, loss, perplexity ----------------
__global__ void k_stats(const float* __restrict__ counts, const float* __restrict__ ema_cs,
                        const int* __restrict__ counter, const int* __restrict__ train,
                        const float* __restrict__ loss_part, float* __restrict__ csn,
                        float* __restrict__ outloss, float* __restrict__ outperp) {
  __shared__ float s_n[4], s_e[4], s_l[4], s_tot[1];
  int tid = threadIdx.x;
  float debias = 1.0f - powf(DECAYF, (float)(*counter + 1));
  float nloc = 0.f, eloc = 0.f;
  float lloc = loss_part[tid];
  float avg[32];
  for (int i = 0; i < 32; ++i) {
    int k = tid + i * 256;
    float c = counts[k];
    float h = ema_cs[k] * DECAYF + c * (1.0f - DECAYF);
    float a = h / debias;
    avg[i] = a;
    nloc += a;
    float p = c * (1.0f / 16384.0f);
    eloc += p * logf(p + 1e-10f);
  }
  #pragma unroll
  for (int s = 1; s < 64; s <<= 1) {
    nloc += __shfl_xor(nloc, s, 64);
    eloc += __shfl_xor(eloc, s, 64);
    lloc += __shfl_xor(lloc, s, 64);
  }
  int w = tid >> 6, lane = tid & 63;
  if (lane == 0) { s_n[w] = nloc; s_e[w] = eloc; s_l[w] = lloc; }
  __syncthreads();
  if (tid == 0) {
    float nt = (s_n[0] + s_n[1]) + (s_n[2] + s_n[3]);
    float et = (s_e[0] + s_e[1]) + (s_e[2] + s_e[3]);
    float lt = (s_l[0] + s_l[1]) + (s_l[2] + s_l[3]);
    s_tot[0] = nt;
    outperp[0] = expf(-et);
    outloss[0] = 0.25f * (lt / 4194304.0f);
  }
  __syncthreads();
  float nsum = s_tot[0];
  float denom = nsum + 8192.0f * EPSF;
  for (int i = 0; i < 32; ++i) {
    int k = tid + i * 256;
    csn[k] = (avg[i] + EPSF) / denom * nsum;
  }
}

// ---------------- finalize: transpose dwT + EMA + scale -> out4 [D,K] -------
// grid (K/32, D/32), 256 threads; also covers the eval (copy emb) branch.
__global__ void k_final(const float* __restrict__ dwT, const float* __restrict__ ema_dw,
                        const float* __restrict__ emb, const float* __restrict__ csn,
                        const int* __restrict__ counter, const int* __restrict__ train,
                        float* __restrict__ out4) {
  __shared__ float ld[32 * 33];
  int t = threadIdx.x;
  int k0 = blockIdx.x * 32, d0 = blockIdx.y * 32;
  if (*train) {
    {
      int ki = t >> 3, dq = (t & 7) * 4;
      float4 v = *(const float4*)(dwT + (size_t)(k0 + ki) * DD + d0 + dq);
      ld[ki * 33 + dq + 0] = v.x; ld[ki * 33 + dq + 1] = v.y;
      ld[ki * 33 + dq + 2] = v.z; ld[ki * 33 + dq + 3] = v.w;
    }
    __syncthreads();
    int dout = t >> 3, kq = (t & 7) * 4;
    size_t o = (size_t)(d0 + dout) * KK + k0 + kq;
    float4 e = *(const float4*)(ema_dw + o);
    float4 c = *(const float4*)(csn + k0 + kq);
    float inv = 1.0f / (1.0f - powf(DECAYF, (float)(*counter + 1)));
    float4 r;
    r.x = fmaf(e.x, DECAYF, ld[(kq + 0) * 33 + dout]) * inv / c.x;
    r.y = fmaf(e.y, DECAYF, ld[(kq + 1) * 33 + dout]) * inv / c.y;
    r.z = fmaf(e.z, DECAYF, ld[(kq + 2) * 33 + dout]) * inv / c.z;
    r.w = fmaf(e.w, DECAYF, ld[(kq + 3) * 33 + dout]) * inv / c.w;
    *(float4*)(out4 + o) = r;
  } else {
    int dout = t >> 3, kq = (t & 7) * 4;
    size_t o = (size_t)(d0 + dout) * KK + k0 + kq;
    *(float4*)(out4 + o) = *(const float4*)(emb + o);
  }
}

extern "C" void kernel_launch(void* const* d_in, const int* in_sizes, int n_in,
                              void* d_out, int out_size, void* d_ws, size_t ws_size,
                              hipStream_t stream) {
  (void)in_sizes; (void)n_in; (void)out_size; (void)ws_size;
  const float* x      = (const float*)d_in[0];
  const float* emb    = (const float*)d_in[1];
  const float* ema_cs = (const float*)d_in[2];
  const float* ema_dw = (const float*)d_in[3];
  const int*   counter = (const int*)d_in[4];
  const int*   train   = (const int*)d_in[5];

  float* out = (float*)d_out;
  float* outq    = out + O_Q;
  float* outloss = out + O_LOSS;
  float* outperp = out + O_PERP;
  float* outidx  = out + O_IDX;
  float* out4    = out + O_EMB;

  // workspace carve (bytes)
  char* W = (char*)d_ws;
  unsigned short* Ahi  = (unsigned short*)(W);              //  8 MB
  unsigned short* Alo  = (unsigned short*)(W + 8388608);    //  8 MB
  unsigned short* BThi = (unsigned short*)(W + 16777216);   //  4 MB
  unsigned short* BTlo = (unsigned short*)(W + 20971520);   //  4 MB
  float* embT          = (float*)(W + 25165824);            //  8 MB
  float* part1         = (float*)(W + 33554432);            //  4 MB
  float* part2         = (float*)(W + 37748736);            //  4 MB
  int*   partidx       = (int*)(W + 41943040);              //  4 MB
  float* dwT           = part1;                             //  8 MB alias (part1+part2, dead after argmin2)
  unsigned long long* keys = (unsigned long long*)(W + 46137344); // 128 KB
  float* esq           = (float*)(W + 46268416);
  float* csn           = (float*)(W + 46301184);
  float* counts        = (float*)(W + 46333952);            // 8192 floats
  float* loss_part     = (float*)(W + 46366720);            // 256 floats
  int*   listc         = (int*)(W + 46367744);
  int*   list          = (int*)(W + 46367748);              // 16384 ints
  int*   idxw          = (int*)(W + 46433288);              // 16384 ints

  // zero counts + loss_part + listc (contiguous), keys to +inf (top-of-capture only)
  hipMemsetAsync(counts, 0, 32768 + 1024 + 4, stream);
  hipMemsetAsync(keys, 0xFF, NN * sizeof(unsigned long long), stream);

  k_convert_x<<<4096, 256, 0, stream>>>(x, Ahi, Alo);
  k_convert_e<<<dim3(256, 8), 256, 0, stream>>>(emb, BThi, BTlo, embT);
  k_colsq<<<256, 256, 0, stream>>>(emb, esq);
  k_dist_mfma<<<dim3(64, 128), 256, 0, stream>>>(Ahi, Alo, BThi, BTlo, esq, part1, part2, partidx);
  k_argmin2<<<4096, 256, 0, stream>>>(part1, part2, partidx, idxw, listc, list);
  k_zero<<<2048, 256, 0, stream>>>((float4*)dwT); // 2048*256*16B = exactly 8 MB
  k_rescore<<<256, 256, 0, stream>>>(x, emb, listc, list, keys);
  k_fixup<<<1, 256, 0, stream>>>(listc, list, keys, idxw);
  k_gather<<<4096, 256, 0, stream>>>(x, embT, idxw, train, outq, outidx, dwT, counts, loss_part);
  k_stats<<<1, 256, 0, stream>>>(counts, ema_cs, counter, train, loss_part, csn, outloss, outperp);
  k_final<<<dim3(256, 8), 256, 0, stream>>>(dwT, ema_dw, emb, csn, counter, train, out4);
}

// Round 8
// 385.657 us; speedup vs baseline: 6.0584x; 1.2105x over previous
//
#include <hip/hip_runtime.h>
#include <math.h>

#define DD 256
#define KK 8192
#define NN 16384
#define DECAYF 0.99f
#define EPSF 1e-5f
#define TAU 4e-3f

// output layout (floats)
#define O_Q    0
#define O_LOSS 4194304
#define O_PERP 4194305
#define O_IDX  4194306
#define O_EMB  4210690

typedef float f32x4 __attribute__((ext_vector_type(4)));
typedef _Float16 f16x8 __attribute__((ext_vector_type(8)));

__device__ __forceinline__ unsigned short f2h(float f) {
  union { _Float16 h; unsigned short u; } c;
  c.h = (_Float16)f;
  return c.u;
}

__device__ __forceinline__ void gll16(const void* g, void* l) {
  __builtin_amdgcn_global_load_lds((const __attribute__((address_space(1))) void*)g,
                                   (__attribute__((address_space(3))) void*)l, 16, 0, 0);
}

// ---------------- x -> fp16 [N,D]; blocks 0..31 also zero esq ----------------
__global__ void k_convert_x(const float* __restrict__ x, unsigned short* __restrict__ Ah,
                            float* __restrict__ esq) {
  int i = blockIdx.x * 256 + threadIdx.x; // float4 index, 1048576 total
  if (blockIdx.x < 32) esq[blockIdx.x * 256 + threadIdx.x] = 0.f;
  float4 v = ((const float4*)x)[i];
  ushort4 h;
  h.x = f2h(v.x); h.y = f2h(v.y); h.z = f2h(v.z); h.w = f2h(v.w);
  ((ushort4*)Ah)[i] = h;
}

// ------- transpose emb [D,K] -> embT fp32 [K,D] + Eh fp16 [K,D] + esq -------
__global__ void k_convert_e(const float* __restrict__ emb, unsigned short* __restrict__ Eh,
                            float* __restrict__ embT, float* __restrict__ esq) {
  __shared__ float ld[32 * 33];
  int t = threadIdx.x;
  int k0 = blockIdx.x * 32, d0 = blockIdx.y * 32;
  {
    int din = t >> 3, kq = (t & 7) * 4;
    float4 v = *(const float4*)(emb + (size_t)(d0 + din) * KK + k0 + kq);
    ld[din * 33 + kq + 0] = v.x; ld[din * 33 + kq + 1] = v.y;
    ld[din * 33 + kq + 2] = v.z; ld[din * 33 + kq + 3] = v.w;
  }
  __syncthreads();
  int kout = t >> 3, dq = (t & 7) * 4;
  float f0 = ld[(dq + 0) * 33 + kout], f1 = ld[(dq + 1) * 33 + kout];
  float f2 = ld[(dq + 2) * 33 + kout], f3 = ld[(dq + 3) * 33 + kout];
  size_t o = (size_t)(k0 + kout) * DD + d0 + dq;
  float4 fv; fv.x = f0; fv.y = f1; fv.z = f2; fv.w = f3;
  *(float4*)(embT + o) = fv;
  ushort4 hv;
  hv.x = f2h(f0); hv.y = f2h(f1); hv.z = f2h(f2); hv.w = f2h(f3);
  *(ushort4*)(Eh + o) = hv;
  // esq partial: 8 threads (t&7) share kout; reduce then one atomic
  float p = (f0 * f0 + f1 * f1) + (f2 * f2 + f3 * f3);
  p += __shfl_xor(p, 1, 64);
  p += __shfl_xor(p, 2, 64);
  p += __shfl_xor(p, 4, 64);
  if ((t & 7) == 0) atomicAdd(esq + k0 + kout, p);
}

// ---------------- zero dwT: 8 MB = 2048 blocks x 256 threads x 16 B --------
__global__ void k_zero(float4* __restrict__ p) {
  p[(size_t)blockIdx.x * 256 + threadIdx.x] = make_float4(0.f, 0.f, 0.f, 0.f);
}

// ---------------- MFMA distance screening (fp16 single GEMM) ----------------
// grid (64 kb, 128 nb); 256 threads = 4 waves; tile 128x128; BD=64 per iter.
// dd = esq[k] - 2*(xh.eh); error absorbed by TAU=4e-3 + fp64 rescore.
__launch_bounds__(256, 2)
__global__ void k_dist_mfma(const unsigned short* __restrict__ Ah, const unsigned short* __restrict__ Bh,
                            const float* __restrict__ esq,
                            float* __restrict__ part1, float* __restrict__ part2,
                            int* __restrict__ partidx) {
  __shared__ __align__(16) unsigned short sA[8192]; // 128 rows x 64 f16 (16 KB)
  __shared__ __align__(16) unsigned short sB[8192];

  const int tid = threadIdx.x;
  const int w = tid >> 6, lane = tid & 63;
  const int kb = blockIdx.x, nb = blockIdx.y;
  const int row0 = nb * 128, col0 = kb * 128;

  // staging: call s covers rows (w*4+s)*8 + (lane>>3); chunk (lane&7)^(r&7)
  size_t gA[4], gB[4];
  int lbase[4];
  #pragma unroll
  for (int s = 0; s < 4; ++s) {
    int r = (w * 4 + s) * 8 + (lane >> 3);
    int c = (lane & 7) ^ (r & 7);
    gA[s] = (size_t)(row0 + r) * DD + c * 8;
    gB[s] = (size_t)(col0 + r) * DD + c * 8;
    lbase[s] = (w * 4 + s) * 512;
  }
  const int m = lane & 15, q = lane >> 4;

  f32x4 acc[2][8];
  #pragma unroll
  for (int i = 0; i < 2; ++i)
    #pragma unroll
    for (int j = 0; j < 8; ++j) acc[i][j] = (f32x4)0.f;

  for (int it = 0; it < 4; ++it) {
    const int d0 = it * 64;
    __syncthreads();
    #pragma unroll
    for (int s = 0; s < 4; ++s) {
      gll16(Ah + gA[s] + d0, sA + lbase[s]);
      gll16(Bh + gB[s] + d0, sB + lbase[s]);
    }
    __syncthreads();
    #pragma unroll
    for (int kk = 0; kk < 2; ++kk) {
      f16x8 a[2];
      #pragma unroll
      for (int i = 0; i < 2; ++i) {
        int wr = w * 32 + i * 16 + m;
        int slot = (kk * 4 + q) ^ (wr & 7);
        a[i] = *(const f16x8*)(sA + wr * 64 + slot * 8);
      }
      #pragma unroll
      for (int j = 0; j < 8; ++j) {
        int cn = j * 16 + m;
        int slot = (kk * 4 + q) ^ (cn & 7);
        f16x8 b = *(const f16x8*)(sB + cn * 64 + slot * 8);
        acc[0][j] = __builtin_amdgcn_mfma_f32_16x16x32_f16(a[0], b, acc[0][j], 0, 0, 0);
        acc[1][j] = __builtin_amdgcn_mfma_f32_16x16x32_f16(a[1], b, acc[1][j], 0, 0, 0);
      }
    }
  }

  float eq[8];
  #pragma unroll
  for (int j = 0; j < 8; ++j) eq[j] = esq[col0 + j * 16 + m];

  #pragma unroll
  for (int i = 0; i < 2; ++i) {
    #pragma unroll
    for (int reg = 0; reg < 4; ++reg) {
      float m1 = 3.402823466e+38f, m2 = 3.402823466e+38f;
      int bi = 0;
      #pragma unroll
      for (int j = 0; j < 8; ++j) {
        float dd = fmaf(-2.0f, acc[i][j][reg], eq[j]);
        if (dd < m1) { m2 = m1; m1 = dd; bi = col0 + j * 16 + m; }
        else if (dd < m2) m2 = dd;
      }
      #pragma unroll
      for (int st = 1; st < 16; st <<= 1) {
        float ov = __shfl_xor(m1, st, 64);
        int   oi = __shfl_xor(bi, st, 64);
        float o2 = __shfl_xor(m2, st, 64);
        float big = fmaxf(m1, ov);
        m2 = fminf(fminf(m2, o2), big);
        if (ov < m1 || (ov == m1 && oi < bi)) { m1 = ov; bi = oi; }
      }
      if (m == 0) {
        int prow = row0 + w * 32 + i * 16 + q * 4 + reg;
        int pidx = prow * 64 + kb;
        part1[pidx] = m1; part2[pidx] = m2; partidx[pidx] = bi;
      }
    }
  }
}

// ---------------- reduce 64 k-block partials per row ----------------
__global__ void k_argmin2(const float* __restrict__ part1, const float* __restrict__ part2,
                          const int* __restrict__ partidx, int* __restrict__ idxw,
                          int* __restrict__ listc, int* __restrict__ list) {
  int w = threadIdx.x >> 6, l = threadIdx.x & 63;
  int row = blockIdx.x * 4 + w;
  int base = row * 64 + l;
  float m1 = part1[base], m2 = part2[base];
  int bi = partidx[base];
  #pragma unroll
  for (int st = 1; st < 64; st <<= 1) {
    float ov = __shfl_xor(m1, st, 64);
    int   oi = __shfl_xor(bi, st, 64);
    float o2 = __shfl_xor(m2, st, 64);
    float big = fmaxf(m1, ov);
    m2 = fminf(fminf(m2, o2), big);
    if (ov < m1 || (ov == m1 && oi < bi)) { m1 = ov; bi = oi; }
  }
  if (l == 0) {
    idxw[row] = bi;
    if (m2 - m1 < TAU) { int pos = atomicAdd(listc, 1); list[pos] = row; }
  }
}

// ---------------- fp64 rescore of near-tie rows (parallel over rows) --------
// grid (256 k-slices, 8 row-stripes); block stages its 32-col emb slice once.
__global__ void k_rescore(const float* __restrict__ x, const float* __restrict__ emb,
                          const int* __restrict__ listc, const int* __restrict__ list,
                          unsigned long long* __restrict__ keys) {
  __shared__ float se[8192];
  __shared__ double red[256];
  const int t = threadIdx.x;
  const int k0 = blockIdx.x * 32;
  #pragma unroll
  for (int i = 0; i < 32; ++i) {
    int elem = i * 256 + t;
    int d = elem >> 5, c = elem & 31;
    se[d * 32 + c] = emb[(size_t)d * KK + k0 + c];
  }
  __syncthreads();
  const int c = t & 31, p = t >> 5;
  int cnt = *listc;
  for (int li = blockIdx.y; li < cnt; li += gridDim.y) {
    int row = list[li];
    const float* xr = x + (size_t)row * DD;
    double acc = 0.0;
    #pragma unroll
    for (int j = 0; j < 32; ++j) {
      int d = p * 32 + j;
      double df = (double)xr[d] - (double)se[d * 32 + c];
      acc = fma(df, df, acc);
    }
    red[c * 8 + p] = acc;
    __syncthreads();
    if (t < 64) {
      unsigned long long key = ~0ull;
      if (t < 32) {
        double dist = 0.0;
        #pragma unroll
        for (int qq = 0; qq < 8; ++qq) dist += red[t * 8 + qq];
        key = ((unsigned long long)__double_as_longlong(dist) & ~0x1FFFull)
              | (unsigned long long)(k0 + t);
      }
      #pragma unroll
      for (int s = 1; s < 64; s <<= 1) {
        unsigned long long o = __shfl_xor(key, s, 64);
        if (o < key) key = o;
      }
      if (t == 0) atomicMin(&keys[row], key);
    }
    __syncthreads();
  }
}

// ---------------- gather + outputs + scatter stats ----------------
// keys[n] != ~0 marks a rescored row (replaces k_fixup).
__global__ void k_gather(const float* __restrict__ x, const float* __restrict__ embT,
                         const int* __restrict__ idxw, const unsigned long long* __restrict__ keys,
                         const int* __restrict__ train,
                         float* __restrict__ outq, float* __restrict__ outidx,
                         float* __restrict__ dwT, float* __restrict__ counts,
                         float* __restrict__ loss_part) {
  int w = threadIdx.x >> 6, l = threadIdx.x & 63;
  int n = blockIdx.x * 4 + w;
  unsigned long long kv = keys[n];
  int k = (kv != ~0ull) ? (int)(kv & 0x1FFFull) : idxw[n];
  float4 xv = ((const float4*)(x + (size_t)n * DD))[l];
  float4 qv = ((const float4*)(embT + (size_t)k * DD))[l];
  int d = l * 4;

  ((float4*)(outq + (size_t)n * DD))[l] = qv; // x + (q - x) == q

  float e0 = qv.x - xv.x, e1 = qv.y - xv.y, e2 = qv.z - xv.z, e3 = qv.w - xv.w;
  float ls = (e0 * e0 + e1 * e1) + (e2 * e2 + e3 * e3);

  if (*train) {
    const float wdw = 1.0f - DECAYF;
    float* base = dwT + (size_t)k * DD + d;
    atomicAdd(base + 0, xv.x * wdw);
    atomicAdd(base + 1, xv.y * wdw);
    atomicAdd(base + 2, xv.z * wdw);
    atomicAdd(base + 3, xv.w * wdw);
  }

  #pragma unroll
  for (int s = 1; s < 64; s <<= 1) ls += __shfl_xor(ls, s, 64);
  if (l == 0) {
    atomicAdd(&loss_part[blockIdx.x & 255], ls);
    atomicAdd(&counts[k], 1.0f);
    outidx[n] = (float)k;
  }
}

// ---------------- EMA cluster stats, loss, perplexity ----------------
__global__ void k_stats(const float* __restrict__ counts, const float* __restrict__ ema_cs,
                        const int* __restrict__ counter, const int* __restrict__ train,
                        const float* __restrict__ loss_part, float* __restrict__ csn,
                        float* __restrict__ outloss, float* __restrict__ outperp) {
  __shared__ float s_n[4], s_e[4], s_l[4], s_tot[1];
  int tid = threadIdx.x;
  float debias = 1.0f - powf(DECAYF, (float)(*counter + 1));
  float nloc = 0.f, eloc = 0.f;
  float lloc = loss_part[tid];
  float avg[32];
  for (int i = 0; i < 32; ++i) {
    int k = tid + i * 256;
    float c = counts[k];
    float h = ema_cs[k] * DECAYF + c * (1.0f - DECAYF);
    float a = h / debias;
    avg[i] = a;
    nloc += a;
    float p = c * (1.0f / 16384.0f);
    eloc += p * logf(p + 1e-10f);
  }
  #pragma unroll
  for (int s = 1; s < 64; s <<= 1) {
    nloc += __shfl_xor(nloc, s, 64);
    eloc += __shfl_xor(eloc, s, 64);
    lloc += __shfl_xor(lloc, s, 64);
  }
  int w = tid >> 6, lane = tid & 63;
  if (lane == 0) { s_n[w] = nloc; s_e[w] = eloc; s_l[w] = lloc; }
  __syncthreads();
  if (tid == 0) {
    float nt = (s_n[0] + s_n[1]) + (s_n[2] + s_n[3]);
    float et = (s_e[0] + s_e[1]) + (s_e[2] + s_e[3]);
    float lt = (s_l[0] + s_l[1]) + (s_l[2] + s_l[3]);
    s_tot[0] = nt;
    outperp[0] = expf(-et);
    outloss[0] = 0.25f * (lt / 4194304.0f);
  }
  __syncthreads();
  float nsum = s_tot[0];
  float denom = nsum + 8192.0f * EPSF;
  for (int i = 0; i < 32; ++i) {
    int k = tid + i * 256;
    csn[k] = (avg[i] + EPSF) / denom * nsum;
  }
}

// ---------------- finalize: transpose dwT + EMA + scale -> out4 [D,K] -------
__global__ void k_final(const float* __restrict__ dwT, const float* __restrict__ ema_dw,
                        const float* __restrict__ emb, const float* __restrict__ csn,
                        const int* __restrict__ counter, const int* __restrict__ train,
                        float* __restrict__ out4) {
  __shared__ float ld[32 * 33];
  int t = threadIdx.x;
  int k0 = blockIdx.x * 32, d0 = blockIdx.y * 32;
  if (*train) {
    {
      int ki = t >> 3, dq = (t & 7) * 4;
      float4 v = *(const float4*)(dwT + (size_t)(k0 + ki) * DD + d0 + dq);
      ld[ki * 33 + dq + 0] = v.x; ld[ki * 33 + dq + 1] = v.y;
      ld[ki * 33 + dq + 2] = v.z; ld[ki * 33 + dq + 3] = v.w;
    }
    __syncthreads();
    int dout = t >> 3, kq = (t & 7) * 4;
    size_t o = (size_t)(d0 + dout) * KK + k0 + kq;
    float4 e = *(const float4*)(ema_dw + o);
    float4 c = *(const float4*)(csn + k0 + kq);
    float inv = 1.0f / (1.0f - powf(DECAYF, (float)(*counter + 1)));
    float4 r;
    r.x = fmaf(e.x, DECAYF, ld[(kq + 0) * 33 + dout]) * inv / c.x;
    r.y = fmaf(e.y, DECAYF, ld[(kq + 1) * 33 + dout]) * inv / c.y;
    r.z = fmaf(e.z, DECAYF, ld[(kq + 2) * 33 + dout]) * inv / c.z;
    r.w = fmaf(e.w, DECAYF, ld[(kq + 3) * 33 + dout]) * inv / c.w;
    *(float4*)(out4 + o) = r;
  } else {
    int dout = t >> 3, kq = (t & 7) * 4;
    size_t o = (size_t)(d0 + dout) * KK + k0 + kq;
    *(float4*)(out4 + o) = *(const float4*)(emb + o);
  }
}

extern "C" void kernel_launch(void* const* d_in, const int* in_sizes, int n_in,
                              void* d_out, int out_size, void* d_ws, size_t ws_size,
                              hipStream_t stream) {
  (void)in_sizes; (void)n_in; (void)out_size; (void)ws_size;
  const float* x      = (const float*)d_in[0];
  const float* emb    = (const float*)d_in[1];
  const float* ema_cs = (const float*)d_in[2];
  const float* ema_dw = (const float*)d_in[3];
  const int*   counter = (const int*)d_in[4];
  const int*   train   = (const int*)d_in[5];

  float* out = (float*)d_out;
  float* outq    = out + O_Q;
  float* outloss = out + O_LOSS;
  float* outperp = out + O_PERP;
  float* outidx  = out + O_IDX;
  float* out4    = out + O_EMB;

  // workspace carve (bytes)
  char* W = (char*)d_ws;
  unsigned short* Ah   = (unsigned short*)(W);              //  8 MB fp16 x
  unsigned short* Eh   = (unsigned short*)(W + 8388608);    //  4 MB fp16 embT
  float* embT          = (float*)(W + 12582912);            //  8 MB fp32 embT
  float* part1         = (float*)(W + 20971520);            //  4 MB
  float* part2         = (float*)(W + 25165824);            //  4 MB
  int*   partidx       = (int*)(W + 29360128);              //  4 MB
  float* dwT           = part1;                             //  8 MB alias (dead after argmin2)
  unsigned long long* keys = (unsigned long long*)(W + 33554432); // 128 KB
  float* esq           = (float*)(W + 33685504);            // 32 KB
  float* csn           = (float*)(W + 33718272);            // 32 KB
  float* counts        = (float*)(W + 33751040);            // 32 KB
  float* loss_part     = (float*)(W + 33783808);            // 1 KB
  int*   listc         = (int*)(W + 33784832);
  int*   list          = (int*)(W + 33784836);              // 64 KB
  int*   idxw          = (int*)(W + 33850372);              // 64 KB

  // zero counts + loss_part + listc (contiguous); keys to +inf
  hipMemsetAsync(counts, 0, 32768 + 1024 + 4, stream);
  hipMemsetAsync(keys, 0xFF, NN * sizeof(unsigned long long), stream);

  k_convert_x<<<4096, 256, 0, stream>>>(x, Ah, esq);
  k_convert_e<<<dim3(256, 8), 256, 0, stream>>>(emb, Eh, embT, esq);
  k_dist_mfma<<<dim3(64, 128), 256, 0, stream>>>(Ah, Eh, esq, part1, part2, partidx);
  k_argmin2<<<4096, 256, 0, stream>>>(part1, part2, partidx, idxw, listc, list);
  k_zero<<<2048, 256, 0, stream>>>((float4*)dwT); // exactly 8 MB
  k_rescore<<<dim3(256, 8), 256, 0, stream>>>(x, emb, listc, list, keys);
  k_gather<<<4096, 256, 0, stream>>>(x, embT, idxw, keys, train, outq, outidx, dwT, counts, loss_part);
  k_stats<<<1, 256, 0, stream>>>(counts, ema_cs, counter, train, loss_part, csn, outloss, outperp);
  k_final<<<dim3(256, 8), 256, 0, stream>>>(dwT, ema_dw, emb, csn, counter, train, out4);
}